// Round 1
// baseline (9866.783 us; speedup 1.0000x reference)
//
#include <hip/hip_runtime.h>

#define H_DIM   2048
#define N_HALF  1024
#define B_SZ    128
#define T_STEPS 512
#define IN_DIM  64
#define ALPHA_F 0.05f
#define OMA_F   0.95f   // 1 - ALPHA

typedef __bf16 bf16x8 __attribute__((ext_vector_type(8)));
typedef float  f32x4  __attribute__((ext_vector_type(4)));

// round-to-nearest-even f32 -> bf16 bits
__device__ __forceinline__ unsigned short f2bf(float f) {
    union { float f; unsigned int u; } v; v.f = f;
    unsigned int u = v.u;
    u += 0x7FFFu + ((u >> 16) & 1u);
    return (unsigned short)(u >> 16);
}

// ---------------------------------------------------------------------------
// Wt[j][k] = bf16(W[k][j])  (transpose + convert, LDS-tiled 64x64)
// grid (32,32), block (64,4)
// ---------------------------------------------------------------------------
__global__ void wt_kernel(const float* __restrict__ W, unsigned short* __restrict__ Wt) {
    __shared__ float tile[64][65];
    const int jb = blockIdx.x * 64;
    const int kb = blockIdx.y * 64;
    const int tx = threadIdx.x;   // 0..63
    const int ty = threadIdx.y;   // 0..3
    #pragma unroll
    for (int r = ty; r < 64; r += 4)
        tile[r][tx] = W[(size_t)(kb + r) * H_DIM + jb + tx];
    __syncthreads();
    #pragma unroll
    for (int r = ty; r < 64; r += 4)
        Wt[(size_t)(jb + r) * H_DIM + kb + tx] = f2bf(tile[tx][r]);
}

// ---------------------------------------------------------------------------
// vel[t,b] = sum_i x[t,b,i] * w_in[i]
// ---------------------------------------------------------------------------
__global__ void vel_kernel(const float* __restrict__ x, const float* __restrict__ w_in,
                           float* __restrict__ vel) {
    const int tb = blockIdx.x * blockDim.x + threadIdx.x;
    if (tb >= T_STEPS * B_SZ) return;
    const float* xp = x + (size_t)tb * IN_DIM;
    float s = 0.f;
    #pragma unroll
    for (int i = 0; i < IN_DIM; i += 4) {
        float4 xv = *reinterpret_cast<const float4*>(xp + i);
        float4 wv = *reinterpret_cast<const float4*>(w_in + i);
        s += xv.x * wv.x + xv.y * wv.y + xv.z * wv.z + xv.w * wv.w;
    }
    vel[tb] = s;
}

// ---------------------------------------------------------------------------
// hbf[i] = bf16(hidden0[i])
// ---------------------------------------------------------------------------
__global__ void hbf_init_kernel(const float* __restrict__ h0, unsigned short* __restrict__ hbf) {
    const int i = blockIdx.x * blockDim.x + threadIdx.x;
    hbf[i] = f2bf(h0[i]);
}

// ---------------------------------------------------------------------------
// One recurrence step:
//   h2h = h_{t-1} @ W          (bf16 MFMA, Wt is W^T)
//   h_t = 0.95*h_{t-1} + 0.05*relu(1 + vel*gamma + h2h)
// writes acts[t] (f32) and hbf_out (bf16); optionally the hT tail.
// grid 256 blocks x 256 threads; wave owns one 16x16 output tile,
// K=2048 split into two independent accumulator chains.
// ---------------------------------------------------------------------------
__global__ __launch_bounds__(256) void step_kernel(
        const unsigned short* __restrict__ Wt,
        const unsigned short* __restrict__ hbf_in,
        unsigned short* __restrict__ hbf_out,
        const float* __restrict__ vel_t,     // vel + t*B
        const float* __restrict__ hprev,     // acts[t-1] or hidden0 (f32)
        float* __restrict__ acts_t,          // acts[t]
        float* __restrict__ outT) {          // hT tail or nullptr
    const int lane = threadIdx.x & 63;
    const int w    = threadIdx.x >> 6;          // 0..3
    const int bid  = blockIdx.x;
    const int mg   = bid >> 7;                  // 0..1
    const int n    = bid & 127;                 // 0..127
    const int base_b = mg * 64 + w * 16;
    const int base_j = n * 16;

    const int r16  = lane & 15;
    const int koff = (lane >> 4) * 8;

    // A: h rows (lane&15 = row, 8 contiguous k); B: Wt rows = W columns
    const bf16x8* Ap = reinterpret_cast<const bf16x8*>(
        hbf_in + (size_t)(base_b + r16) * H_DIM + koff);
    const bf16x8* Bp = reinterpret_cast<const bf16x8*>(
        Wt + (size_t)(base_j + r16) * H_DIM + koff);

    f32x4 acc0 = {0.f, 0.f, 0.f, 0.f};
    f32x4 acc1 = {0.f, 0.f, 0.f, 0.f};
    // k advances 32 bf16 per iter = 4 bf16x8 vectors; chain1 offset = 1024 bf16 = 128 vecs
    #pragma unroll 4
    for (int kk = 0; kk < 32; ++kk) {
        bf16x8 a0 = Ap[kk * 4];
        bf16x8 b0 = Bp[kk * 4];
        bf16x8 a1 = Ap[kk * 4 + 128];
        bf16x8 b1 = Bp[kk * 4 + 128];
        acc0 = __builtin_amdgcn_mfma_f32_16x16x32_bf16(a0, b0, acc0, 0, 0, 0);
        acc1 = __builtin_amdgcn_mfma_f32_16x16x32_bf16(a1, b1, acc1, 0, 0, 0);
    }
    f32x4 h2h = acc0 + acc1;

    const int j = base_j + r16;
    const float gamma = (j < N_HALF) ? -1.0f : 1.0f;
    const int brow0 = base_b + (lane >> 4) * 4;
    #pragma unroll
    for (int i = 0; i < 4; ++i) {
        const int b = brow0 + i;
        const float v  = vel_t[b];
        const float hp = hprev[(size_t)b * H_DIM + j];
        const float pre = fmaf(v, gamma, 1.0f) + h2h[i];
        const float hn = OMA_F * hp + ALPHA_F * fmaxf(pre, 0.0f);
        acts_t[(size_t)b * H_DIM + j] = hn;
        hbf_out[(size_t)b * H_DIM + j] = f2bf(hn);
        if (outT) outT[(size_t)b * H_DIM + j] = hn;
    }
}

// ---------------------------------------------------------------------------
extern "C" void kernel_launch(void* const* d_in, const int* in_sizes, int n_in,
                              void* d_out, int out_size, void* d_ws, size_t ws_size,
                              hipStream_t stream) {
    const float* x       = (const float*)d_in[0];  // [T,B,IN]
    const float* hidden0 = (const float*)d_in[1];  // [B,H]
    const float* w_attr  = (const float*)d_in[2];  // [H,H]
    const float* w_in    = (const float*)d_in[3];  // [1,IN]

    float* acts = (float*)d_out;                               // [T,B,H]
    float* outT = acts + (size_t)T_STEPS * B_SZ * H_DIM;       // [B,H]

    unsigned char* ws = (unsigned char*)d_ws;
    unsigned short* Wt   = (unsigned short*)ws;                             // 8 MB
    unsigned short* hbf0 = (unsigned short*)(ws + ((size_t)8 << 20));       // 512 KB
    unsigned short* hbf1 = hbf0 + (size_t)B_SZ * H_DIM;                     // 512 KB
    float* vel = (float*)(ws + ((size_t)8 << 20) + (size_t)2 * B_SZ * H_DIM * 2); // 256 KB

    wt_kernel<<<dim3(32, 32), dim3(64, 4), 0, stream>>>(w_attr, Wt);
    vel_kernel<<<(T_STEPS * B_SZ + 255) / 256, 256, 0, stream>>>(x, w_in, vel);
    hbf_init_kernel<<<(B_SZ * H_DIM + 255) / 256, 256, 0, stream>>>(hidden0, hbf0);

    for (int t = 0; t < T_STEPS; ++t) {
        const unsigned short* hin = (t & 1) ? hbf1 : hbf0;
        unsigned short* hout      = (t & 1) ? hbf0 : hbf1;
        const float* hprev = (t == 0) ? hidden0 : acts + (size_t)(t - 1) * B_SZ * H_DIM;
        step_kernel<<<256, 256, 0, stream>>>(
            Wt, hin, hout, vel + (size_t)t * B_SZ, hprev,
            acts + (size_t)t * B_SZ * H_DIM,
            (t == T_STEPS - 1) ? outT : nullptr);
    }
}